// Round 1
// baseline (12247.303 us; speedup 1.0000x reference)
//
#include <hip/hip_runtime.h>
#include <hip/hip_bf16.h>

#define N_NODES 50000
#define NODE_F  192
#define EDGE_F  64
#define DIM     256
#define OUT_DIM 2048
#define DEPTH   3
#define M_EDGES 800000

// ---------------------------------------------------------------------------
// attr = [node_attr | zeros(EDGE_F)]  -> [N, 256], one float4 per thread
// ---------------------------------------------------------------------------
__global__ void k_init_attr(const float* __restrict__ node_attr,
                            float* __restrict__ attr) {
    int i = blockIdx.x * 256 + threadIdx.x;   // float4 index over N*64
    int row = i >> 6, q = i & 63;
    if (row >= N_NODES) return;
    float4 v = make_float4(0.f, 0.f, 0.f, 0.f);
    if (q < NODE_F / 4) v = ((const float4*)node_attr)[row * (NODE_F / 4) + q];
    ((float4*)attr)[i] = v;
}

// ---------------------------------------------------------------------------
// scatter: agg[dst] += attr[src] + [0 | edge_attr]
// one wave per edge (64 lanes x float4 = 256 features)
// ---------------------------------------------------------------------------
__global__ void k_scatter(const float* __restrict__ attr,
                          const float* __restrict__ edge_attr,
                          const int* __restrict__ src,
                          const int* __restrict__ dst,
                          float* __restrict__ agg) {
    int i = blockIdx.x * 256 + threadIdx.x;   // over M*64 float4 slots
    int e = i >> 6, q = i & 63;
    if (e >= M_EDGES) return;
    int s = src[e], t = dst[e];
    float4 v = ((const float4*)attr)[(size_t)s * 64 + q];
    if (q >= NODE_F / 4) {
        float4 ea = ((const float4*)edge_attr)[(size_t)e * (EDGE_F / 4) + (q - NODE_F / 4)];
        v.x += ea.x; v.y += ea.y; v.z += ea.z; v.w += ea.w;
    }
    float* p = agg + (size_t)t * DIM + q * 4;
    atomicAdd(p + 0, v.x);
    atomicAdd(p + 1, v.y);
    atomicAdd(p + 2, v.z);
    atomicAdd(p + 3, v.w);
}

// ---------------------------------------------------------------------------
// inner GEMM: attr_new = (attr + agg) @ W + b, in-place on attr.
// Block: 256 thr, 32 rows. Thread: 4 cols x 8 rows.
// Safe in-place: the block's 32-row input tile is fully staged to LDS first.
// ---------------------------------------------------------------------------
__global__ __launch_bounds__(256) void k_inner(const float* __restrict__ attr,
                                               const float* __restrict__ agg,
                                               const float* __restrict__ W,
                                               const float* __restrict__ b,
                                               float* __restrict__ out) {
    __shared__ float4 sV[32][64];   // 32 KB
    int tid  = threadIdx.x;
    int row0 = blockIdx.x * 32;

    for (int i = tid; i < 32 * 64; i += 256) {
        int r = i >> 6, q = i & 63;
        int grow = row0 + r;
        float4 v = make_float4(0.f, 0.f, 0.f, 0.f);
        if (grow < N_NODES) {
            float4 a = ((const float4*)attr)[(size_t)grow * 64 + q];
            float4 g = ((const float4*)agg)[(size_t)grow * 64 + q];
            v = make_float4(a.x + g.x, a.y + g.y, a.z + g.z, a.w + g.w);
        }
        sV[r][q] = v;
    }
    __syncthreads();

    int cg = tid & 63;   // cols 4*cg .. 4*cg+3
    int rg = tid >> 6;   // rows rg*8 .. rg*8+7

    float4 acc[8];
#pragma unroll
    for (int r = 0; r < 8; r++) acc[r] = make_float4(0.f, 0.f, 0.f, 0.f);

    const float4* W4 = (const float4*)W;   // W[k][c], float4 idx k*64 + cg
    for (int k4 = 0; k4 < 64; k4++) {
        float4 w0 = W4[(size_t)(k4 * 4 + 0) * 64 + cg];
        float4 w1 = W4[(size_t)(k4 * 4 + 1) * 64 + cg];
        float4 w2 = W4[(size_t)(k4 * 4 + 2) * 64 + cg];
        float4 w3 = W4[(size_t)(k4 * 4 + 3) * 64 + cg];
#pragma unroll
        for (int r = 0; r < 8; r++) {
            float4 a = sV[rg * 8 + r][k4];
            acc[r].x += a.x * w0.x + a.y * w1.x + a.z * w2.x + a.w * w3.x;
            acc[r].y += a.x * w0.y + a.y * w1.y + a.z * w2.y + a.w * w3.y;
            acc[r].z += a.x * w0.z + a.y * w1.z + a.z * w2.z + a.w * w3.z;
            acc[r].w += a.x * w0.w + a.y * w1.w + a.z * w2.w + a.w * w3.w;
        }
    }

    float4 bb = ((const float4*)b)[cg];
#pragma unroll
    for (int r = 0; r < 8; r++) {
        int grow = row0 + rg * 8 + r;
        if (grow < N_NODES) {
            float4 o = make_float4(acc[r].x + bb.x, acc[r].y + bb.y,
                                   acc[r].z + bb.z, acc[r].w + bb.w);
            ((float4*)out)[(size_t)grow * 64 + cg] = o;
        }
    }
}

// ---------------------------------------------------------------------------
// fp contribution: fp += sum_rows softmax(attr @ W + b)
// Block: 256 thr, 16 rows x 2048 cols. Thread: 16 rows x 8 cols
// (cols 4*tid..4*tid+3 and 1024+4*tid..1024+4*tid+3).
// ---------------------------------------------------------------------------
__global__ __launch_bounds__(256, 2) void k_fp(const float* __restrict__ attr,
                                               const float* __restrict__ W,
                                               const float* __restrict__ b,
                                               float* __restrict__ fp) {
    __shared__ float4 sA[16][64];   // 16 KB
    __shared__ float  sW[16][4];
    int tid  = threadIdx.x;
    int row0 = blockIdx.x * 16;

    for (int i = tid; i < 16 * 64; i += 256) {
        int r = i >> 6, q = i & 63;
        int grow = row0 + r;
        sA[r][q] = (grow < N_NODES) ? ((const float4*)attr)[(size_t)grow * 64 + q]
                                    : make_float4(0.f, 0.f, 0.f, 0.f);
    }
    __syncthreads();

    float4 acc0[16], acc1[16];
#pragma unroll
    for (int r = 0; r < 16; r++) {
        acc0[r] = make_float4(0.f, 0.f, 0.f, 0.f);
        acc1[r] = make_float4(0.f, 0.f, 0.f, 0.f);
    }

    const float4* W4 = (const float4*)W;   // row k = k*512 float4s
    for (int k4 = 0; k4 < 64; k4++) {
        size_t base = (size_t)(k4 * 4) * 512;
        float4 w00 = W4[base + 0 * 512 + tid];
        float4 w01 = W4[base + 1 * 512 + tid];
        float4 w02 = W4[base + 2 * 512 + tid];
        float4 w03 = W4[base + 3 * 512 + tid];
        float4 w10 = W4[base + 0 * 512 + 256 + tid];
        float4 w11 = W4[base + 1 * 512 + 256 + tid];
        float4 w12 = W4[base + 2 * 512 + 256 + tid];
        float4 w13 = W4[base + 3 * 512 + 256 + tid];
#pragma unroll
        for (int r = 0; r < 16; r++) {
            float4 a = sA[r][k4];
            acc0[r].x += a.x * w00.x + a.y * w01.x + a.z * w02.x + a.w * w03.x;
            acc0[r].y += a.x * w00.y + a.y * w01.y + a.z * w02.y + a.w * w03.y;
            acc0[r].z += a.x * w00.z + a.y * w01.z + a.z * w02.z + a.w * w03.z;
            acc0[r].w += a.x * w00.w + a.y * w01.w + a.z * w02.w + a.w * w03.w;
            acc1[r].x += a.x * w10.x + a.y * w11.x + a.z * w12.x + a.w * w13.x;
            acc1[r].y += a.x * w10.y + a.y * w11.y + a.z * w12.y + a.w * w13.y;
            acc1[r].z += a.x * w10.z + a.y * w11.z + a.z * w12.z + a.w * w13.z;
            acc1[r].w += a.x * w10.w + a.y * w11.w + a.z * w12.w + a.w * w13.w;
        }
    }

    // bias
    float4 b0 = ((const float4*)b)[tid];
    float4 b1 = ((const float4*)b)[256 + tid];
#pragma unroll
    for (int r = 0; r < 16; r++) {
        acc0[r].x += b0.x; acc0[r].y += b0.y; acc0[r].z += b0.z; acc0[r].w += b0.w;
        acc1[r].x += b1.x; acc1[r].y += b1.y; acc1[r].z += b1.z; acc1[r].w += b1.w;
    }

    int lane = tid & 63, wid = tid >> 6;

    // row max
    float m[16];
#pragma unroll
    for (int r = 0; r < 16; r++) {
        float v = fmaxf(fmaxf(acc0[r].x, acc0[r].y), fmaxf(acc0[r].z, acc0[r].w));
        v = fmaxf(v, fmaxf(fmaxf(acc1[r].x, acc1[r].y), fmaxf(acc1[r].z, acc1[r].w)));
        m[r] = v;
    }
#pragma unroll
    for (int off = 32; off > 0; off >>= 1)
#pragma unroll
        for (int r = 0; r < 16; r++) m[r] = fmaxf(m[r], __shfl_xor(m[r], off));
    if (lane == 0)
#pragma unroll
        for (int r = 0; r < 16; r++) sW[r][wid] = m[r];
    __syncthreads();
#pragma unroll
    for (int r = 0; r < 16; r++)
        m[r] = fmaxf(fmaxf(sW[r][0], sW[r][1]), fmaxf(sW[r][2], sW[r][3]));
    __syncthreads();

    // exp + row sum
    float l[16];
#pragma unroll
    for (int r = 0; r < 16; r++) {
        acc0[r].x = __expf(acc0[r].x - m[r]); acc0[r].y = __expf(acc0[r].y - m[r]);
        acc0[r].z = __expf(acc0[r].z - m[r]); acc0[r].w = __expf(acc0[r].w - m[r]);
        acc1[r].x = __expf(acc1[r].x - m[r]); acc1[r].y = __expf(acc1[r].y - m[r]);
        acc1[r].z = __expf(acc1[r].z - m[r]); acc1[r].w = __expf(acc1[r].w - m[r]);
        l[r] = acc0[r].x + acc0[r].y + acc0[r].z + acc0[r].w
             + acc1[r].x + acc1[r].y + acc1[r].z + acc1[r].w;
    }
#pragma unroll
    for (int off = 32; off > 0; off >>= 1)
#pragma unroll
        for (int r = 0; r < 16; r++) l[r] += __shfl_xor(l[r], off);
    if (lane == 0)
#pragma unroll
        for (int r = 0; r < 16; r++) sW[r][wid] = l[r];
    __syncthreads();

    float rinv[16];
#pragma unroll
    for (int r = 0; r < 16; r++) {
        float tot = sW[r][0] + sW[r][1] + sW[r][2] + sW[r][3];
        rinv[r] = (row0 + r < N_NODES) ? 1.0f / tot : 0.0f;
    }

    // column sums over the 16 rows, then atomic into fp
    float4 cs0 = make_float4(0.f, 0.f, 0.f, 0.f);
    float4 cs1 = make_float4(0.f, 0.f, 0.f, 0.f);
#pragma unroll
    for (int r = 0; r < 16; r++) {
        cs0.x += acc0[r].x * rinv[r]; cs0.y += acc0[r].y * rinv[r];
        cs0.z += acc0[r].z * rinv[r]; cs0.w += acc0[r].w * rinv[r];
        cs1.x += acc1[r].x * rinv[r]; cs1.y += acc1[r].y * rinv[r];
        cs1.z += acc1[r].z * rinv[r]; cs1.w += acc1[r].w * rinv[r];
    }
    atomicAdd(&fp[4 * tid + 0], cs0.x);
    atomicAdd(&fp[4 * tid + 1], cs0.y);
    atomicAdd(&fp[4 * tid + 2], cs0.z);
    atomicAdd(&fp[4 * tid + 3], cs0.w);
    atomicAdd(&fp[1024 + 4 * tid + 0], cs1.x);
    atomicAdd(&fp[1024 + 4 * tid + 1], cs1.y);
    atomicAdd(&fp[1024 + 4 * tid + 2], cs1.z);
    atomicAdd(&fp[1024 + 4 * tid + 3], cs1.w);
}

// ---------------------------------------------------------------------------
extern "C" void kernel_launch(void* const* d_in, const int* in_sizes, int n_in,
                              void* d_out, int out_size, void* d_ws, size_t ws_size,
                              hipStream_t stream) {
    const float* node_attr = (const float*)d_in[0];
    const float* edge_attr = (const float*)d_in[1];
    const int*   edge_src  = (const int*)d_in[2];
    const int*   edge_dst  = (const int*)d_in[3];
    const float* W_inner   = (const float*)d_in[4];
    const float* b_inner   = (const float*)d_in[5];
    const float* W_output  = (const float*)d_in[6];
    const float* b_output  = (const float*)d_in[7];

    float* fp   = (float*)d_out;
    float* attr = (float*)d_ws;                      // N*256 floats (51.2 MB)
    float* agg  = attr + (size_t)N_NODES * DIM;      // N*256 floats (51.2 MB)

    hipMemsetAsync(d_out, 0, OUT_DIM * sizeof(float), stream);

    k_init_attr<<<(N_NODES * 64 + 255) / 256, 256, 0, stream>>>(node_attr, attr);

    k_fp<<<(N_NODES + 15) / 16, 256, 0, stream>>>(attr, W_output, b_output, fp);

    for (int d = 1; d <= DEPTH; d++) {
        hipMemsetAsync(agg, 0, (size_t)N_NODES * DIM * sizeof(float), stream);
        k_scatter<<<(M_EDGES * 64 + 255) / 256, 256, 0, stream>>>(
            attr, edge_attr, edge_src, edge_dst, agg);
        k_inner<<<(N_NODES + 31) / 32, 256, 0, stream>>>(
            attr, agg, W_inner + (size_t)(d - 1) * DIM * DIM,
            b_inner + (size_t)(d - 1) * DIM, attr);
        k_fp<<<(N_NODES + 15) / 16, 256, 0, stream>>>(
            attr, W_output + (size_t)d * DIM * OUT_DIM,
            b_output + (size_t)d * OUT_DIM, fp);
    }
}

// Round 2
// 4772.718 us; speedup vs baseline: 2.5661x; 2.5661x over previous
//
#include <hip/hip_runtime.h>
#include <hip/hip_bf16.h>

#define N_NODES 50000
#define NODE_F  192
#define EDGE_F  64
#define DIM     256
#define OUT_DIM 2048
#define DEPTH   3
#define M_EDGES 800000

// ---------------------------------------------------------------------------
// attr = [node_attr | zeros(EDGE_F)]  -> [N, 256], one float4 per thread
// ---------------------------------------------------------------------------
__global__ void k_init_attr(const float* __restrict__ node_attr,
                            float* __restrict__ attr) {
    int i = blockIdx.x * 256 + threadIdx.x;   // float4 index over N*64
    int row = i >> 6, q = i & 63;
    if (row >= N_NODES) return;
    float4 v = make_float4(0.f, 0.f, 0.f, 0.f);
    if (q < NODE_F / 4) v = ((const float4*)node_attr)[row * (NODE_F / 4) + q];
    ((float4*)attr)[i] = v;
}

// ---------------------------------------------------------------------------
// CSR build: degree histogram -> single-block scan -> edge-index fill
// ---------------------------------------------------------------------------
__global__ void k_degree(const int* __restrict__ dst, int* __restrict__ deg) {
    int e = blockIdx.x * 256 + threadIdx.x;
    if (e < M_EDGES) atomicAdd(&deg[dst[e]], 1);
}

// Single block, 1024 threads. deg[i] -> rowptr (exclusive), and deg[] is
// rewritten in-place as the running cursor (= rowptr[i]) for k_fill.
__global__ __launch_bounds__(1024) void k_scan(int* __restrict__ deg,
                                               int* __restrict__ rowptr) {
    __shared__ int part[1024];
    int t = threadIdx.x;
    const int CH = (N_NODES + 1023) / 1024;   // 49
    int beg = t * CH, end = min(beg + CH, N_NODES);
    int s = 0;
    for (int i = beg; i < end; i++) s += deg[i];
    part[t] = s;
    __syncthreads();
    for (int off = 1; off < 1024; off <<= 1) {
        int v = (t >= off) ? part[t - off] : 0;
        __syncthreads();
        part[t] += v;
        __syncthreads();
    }
    int run = (t == 0) ? 0 : part[t - 1];
    for (int i = beg; i < end; i++) {
        int d = deg[i];
        rowptr[i] = run;
        deg[i] = run;      // cursor for k_fill
        run += d;
    }
    if (t == 1023) rowptr[N_NODES] = run;   // == M_EDGES
}

__global__ void k_fill(const int* __restrict__ dst, int* __restrict__ cursor,
                       int* __restrict__ eidx) {
    int e = blockIdx.x * 256 + threadIdx.x;
    if (e < M_EDGES) {
        int p = atomicAdd(&cursor[dst[e]], 1);
        eidx[p] = e;
    }
}

// ---------------------------------------------------------------------------
// gather: agg[i] = sum_{e : dst[e]==i} (attr[src[e]] + [0 | edge_attr[e]])
// one wave (64 lanes x float4) per node
// ---------------------------------------------------------------------------
__global__ __launch_bounds__(256) void k_gather(const float* __restrict__ attr,
                                                const float* __restrict__ edge_attr,
                                                const int* __restrict__ src,
                                                const int* __restrict__ rowptr,
                                                const int* __restrict__ eidx,
                                                float* __restrict__ agg) {
    int gid = blockIdx.x * 256 + threadIdx.x;
    int node = gid >> 6, q = gid & 63;
    if (node >= N_NODES) return;
    int beg = rowptr[node], end = rowptr[node + 1];
    float4 acc = make_float4(0.f, 0.f, 0.f, 0.f);
    const float4* A4 = (const float4*)attr;
    const float4* E4 = (const float4*)edge_attr;
    for (int i = beg; i < end; i++) {
        int e = eidx[i];          // wave-uniform load (broadcast)
        int s = src[e];
        float4 v = A4[(size_t)s * 64 + q];
        if (q >= NODE_F / 4) {
            float4 ea = E4[(size_t)e * (EDGE_F / 4) + (q - NODE_F / 4)];
            v.x += ea.x; v.y += ea.y; v.z += ea.z; v.w += ea.w;
        }
        acc.x += v.x; acc.y += v.y; acc.z += v.z; acc.w += v.w;
    }
    ((float4*)agg)[(size_t)node * 64 + q] = acc;
}

// ---------------------------------------------------------------------------
// inner GEMM: attr_new = (attr + agg) @ W + b, in-place on attr.
// Block: 256 thr, 32 rows. Thread: 4 cols x 8 rows.
// Safe in-place: the block's 32-row input tile is fully staged to LDS first.
// ---------------------------------------------------------------------------
__global__ __launch_bounds__(256) void k_inner(const float* __restrict__ attr,
                                               const float* __restrict__ agg,
                                               const float* __restrict__ W,
                                               const float* __restrict__ b,
                                               float* __restrict__ out) {
    __shared__ float4 sV[32][64];   // 32 KB
    int tid  = threadIdx.x;
    int row0 = blockIdx.x * 32;

    for (int i = tid; i < 32 * 64; i += 256) {
        int r = i >> 6, q = i & 63;
        int grow = row0 + r;
        float4 v = make_float4(0.f, 0.f, 0.f, 0.f);
        if (grow < N_NODES) {
            float4 a = ((const float4*)attr)[(size_t)grow * 64 + q];
            float4 g = ((const float4*)agg)[(size_t)grow * 64 + q];
            v = make_float4(a.x + g.x, a.y + g.y, a.z + g.z, a.w + g.w);
        }
        sV[r][q] = v;
    }
    __syncthreads();

    int cg = tid & 63;   // cols 4*cg .. 4*cg+3
    int rg = tid >> 6;   // rows rg*8 .. rg*8+7

    float4 acc[8];
#pragma unroll
    for (int r = 0; r < 8; r++) acc[r] = make_float4(0.f, 0.f, 0.f, 0.f);

    const float4* W4 = (const float4*)W;   // W[k][c], float4 idx k*64 + cg
    for (int k4 = 0; k4 < 64; k4++) {
        float4 w0 = W4[(size_t)(k4 * 4 + 0) * 64 + cg];
        float4 w1 = W4[(size_t)(k4 * 4 + 1) * 64 + cg];
        float4 w2 = W4[(size_t)(k4 * 4 + 2) * 64 + cg];
        float4 w3 = W4[(size_t)(k4 * 4 + 3) * 64 + cg];
#pragma unroll
        for (int r = 0; r < 8; r++) {
            float4 a = sV[rg * 8 + r][k4];
            acc[r].x += a.x * w0.x + a.y * w1.x + a.z * w2.x + a.w * w3.x;
            acc[r].y += a.x * w0.y + a.y * w1.y + a.z * w2.y + a.w * w3.y;
            acc[r].z += a.x * w0.z + a.y * w1.z + a.z * w2.z + a.w * w3.z;
            acc[r].w += a.x * w0.w + a.y * w1.w + a.z * w2.w + a.w * w3.w;
        }
    }

    float4 bb = ((const float4*)b)[cg];
#pragma unroll
    for (int r = 0; r < 8; r++) {
        int grow = row0 + rg * 8 + r;
        if (grow < N_NODES) {
            float4 o = make_float4(acc[r].x + bb.x, acc[r].y + bb.y,
                                   acc[r].z + bb.z, acc[r].w + bb.w);
            ((float4*)out)[(size_t)grow * 64 + cg] = o;
        }
    }
}

// ---------------------------------------------------------------------------
// fp contribution: fp += sum_rows softmax(attr @ W + b)
// Block: 256 thr, 16 rows x 2048 cols. Thread: 16 rows x 8 cols
// ---------------------------------------------------------------------------
__global__ __launch_bounds__(256, 2) void k_fp(const float* __restrict__ attr,
                                               const float* __restrict__ W,
                                               const float* __restrict__ b,
                                               float* __restrict__ fp) {
    __shared__ float4 sA[16][64];   // 16 KB
    __shared__ float  sW[16][4];
    int tid  = threadIdx.x;
    int row0 = blockIdx.x * 16;

    for (int i = tid; i < 16 * 64; i += 256) {
        int r = i >> 6, q = i & 63;
        int grow = row0 + r;
        sA[r][q] = (grow < N_NODES) ? ((const float4*)attr)[(size_t)grow * 64 + q]
                                    : make_float4(0.f, 0.f, 0.f, 0.f);
    }
    __syncthreads();

    float4 acc0[16], acc1[16];
#pragma unroll
    for (int r = 0; r < 16; r++) {
        acc0[r] = make_float4(0.f, 0.f, 0.f, 0.f);
        acc1[r] = make_float4(0.f, 0.f, 0.f, 0.f);
    }

    const float4* W4 = (const float4*)W;   // row k = k*512 float4s
    for (int k4 = 0; k4 < 64; k4++) {
        size_t base = (size_t)(k4 * 4) * 512;
        float4 w00 = W4[base + 0 * 512 + tid];
        float4 w01 = W4[base + 1 * 512 + tid];
        float4 w02 = W4[base + 2 * 512 + tid];
        float4 w03 = W4[base + 3 * 512 + tid];
        float4 w10 = W4[base + 0 * 512 + 256 + tid];
        float4 w11 = W4[base + 1 * 512 + 256 + tid];
        float4 w12 = W4[base + 2 * 512 + 256 + tid];
        float4 w13 = W4[base + 3 * 512 + 256 + tid];
#pragma unroll
        for (int r = 0; r < 16; r++) {
            float4 a = sA[r][k4];
            acc0[r].x += a.x * w00.x + a.y * w01.x + a.z * w02.x + a.w * w03.x;
            acc0[r].y += a.x * w00.y + a.y * w01.y + a.z * w02.y + a.w * w03.y;
            acc0[r].z += a.x * w00.z + a.y * w01.z + a.z * w02.z + a.w * w03.z;
            acc0[r].w += a.x * w00.w + a.y * w01.w + a.z * w02.w + a.w * w03.w;
            acc1[r].x += a.x * w10.x + a.y * w11.x + a.z * w12.x + a.w * w13.x;
            acc1[r].y += a.x * w10.y + a.y * w11.y + a.z * w12.y + a.w * w13.y;
            acc1[r].z += a.x * w10.z + a.y * w11.z + a.z * w12.z + a.w * w13.z;
            acc1[r].w += a.x * w10.w + a.y * w11.w + a.z * w12.w + a.w * w13.w;
        }
    }

    // bias
    float4 b0 = ((const float4*)b)[tid];
    float4 b1 = ((const float4*)b)[256 + tid];
#pragma unroll
    for (int r = 0; r < 16; r++) {
        acc0[r].x += b0.x; acc0[r].y += b0.y; acc0[r].z += b0.z; acc0[r].w += b0.w;
        acc1[r].x += b1.x; acc1[r].y += b1.y; acc1[r].z += b1.z; acc1[r].w += b1.w;
    }

    int lane = tid & 63, wid = tid >> 6;

    // row max
    float m[16];
#pragma unroll
    for (int r = 0; r < 16; r++) {
        float v = fmaxf(fmaxf(acc0[r].x, acc0[r].y), fmaxf(acc0[r].z, acc0[r].w));
        v = fmaxf(v, fmaxf(fmaxf(acc1[r].x, acc1[r].y), fmaxf(acc1[r].z, acc1[r].w)));
        m[r] = v;
    }
#pragma unroll
    for (int off = 32; off > 0; off >>= 1)
#pragma unroll
        for (int r = 0; r < 16; r++) m[r] = fmaxf(m[r], __shfl_xor(m[r], off));
    if (lane == 0)
#pragma unroll
        for (int r = 0; r < 16; r++) sW[r][wid] = m[r];
    __syncthreads();
#pragma unroll
    for (int r = 0; r < 16; r++)
        m[r] = fmaxf(fmaxf(sW[r][0], sW[r][1]), fmaxf(sW[r][2], sW[r][3]));
    __syncthreads();

    // exp + row sum
    float l[16];
#pragma unroll
    for (int r = 0; r < 16; r++) {
        acc0[r].x = __expf(acc0[r].x - m[r]); acc0[r].y = __expf(acc0[r].y - m[r]);
        acc0[r].z = __expf(acc0[r].z - m[r]); acc0[r].w = __expf(acc0[r].w - m[r]);
        acc1[r].x = __expf(acc1[r].x - m[r]); acc1[r].y = __expf(acc1[r].y - m[r]);
        acc1[r].z = __expf(acc1[r].z - m[r]); acc1[r].w = __expf(acc1[r].w - m[r]);
        l[r] = acc0[r].x + acc0[r].y + acc0[r].z + acc0[r].w
             + acc1[r].x + acc1[r].y + acc1[r].z + acc1[r].w;
    }
#pragma unroll
    for (int off = 32; off > 0; off >>= 1)
#pragma unroll
        for (int r = 0; r < 16; r++) l[r] += __shfl_xor(l[r], off);
    if (lane == 0)
#pragma unroll
        for (int r = 0; r < 16; r++) sW[r][wid] = l[r];
    __syncthreads();

    float rinv[16];
#pragma unroll
    for (int r = 0; r < 16; r++) {
        float tot = sW[r][0] + sW[r][1] + sW[r][2] + sW[r][3];
        rinv[r] = (row0 + r < N_NODES) ? 1.0f / tot : 0.0f;
    }

    // column sums over the 16 rows, then atomic into fp
    float4 cs0 = make_float4(0.f, 0.f, 0.f, 0.f);
    float4 cs1 = make_float4(0.f, 0.f, 0.f, 0.f);
#pragma unroll
    for (int r = 0; r < 16; r++) {
        cs0.x += acc0[r].x * rinv[r]; cs0.y += acc0[r].y * rinv[r];
        cs0.z += acc0[r].z * rinv[r]; cs0.w += acc0[r].w * rinv[r];
        cs1.x += acc1[r].x * rinv[r]; cs1.y += acc1[r].y * rinv[r];
        cs1.z += acc1[r].z * rinv[r]; cs1.w += acc1[r].w * rinv[r];
    }
    atomicAdd(&fp[4 * tid + 0], cs0.x);
    atomicAdd(&fp[4 * tid + 1], cs0.y);
    atomicAdd(&fp[4 * tid + 2], cs0.z);
    atomicAdd(&fp[4 * tid + 3], cs0.w);
    atomicAdd(&fp[1024 + 4 * tid + 0], cs1.x);
    atomicAdd(&fp[1024 + 4 * tid + 1], cs1.y);
    atomicAdd(&fp[1024 + 4 * tid + 2], cs1.z);
    atomicAdd(&fp[1024 + 4 * tid + 3], cs1.w);
}

// ---------------------------------------------------------------------------
extern "C" void kernel_launch(void* const* d_in, const int* in_sizes, int n_in,
                              void* d_out, int out_size, void* d_ws, size_t ws_size,
                              hipStream_t stream) {
    const float* node_attr = (const float*)d_in[0];
    const float* edge_attr = (const float*)d_in[1];
    const int*   edge_src  = (const int*)d_in[2];
    const int*   edge_dst  = (const int*)d_in[3];
    const float* W_inner   = (const float*)d_in[4];
    const float* b_inner   = (const float*)d_in[5];
    const float* W_output  = (const float*)d_in[6];
    const float* b_output  = (const float*)d_in[7];

    float* fp   = (float*)d_out;
    float* attr = (float*)d_ws;                      // N*256 floats (51.2 MB)
    float* agg  = attr + (size_t)N_NODES * DIM;      // N*256 floats (51.2 MB)
    int*   deg    = (int*)(agg + (size_t)N_NODES * DIM);  // N (doubles as cursor)
    int*   rowptr = deg + N_NODES;                   // N+1
    int*   eidx   = rowptr + N_NODES + 1;            // M

    hipMemsetAsync(d_out, 0, OUT_DIM * sizeof(float), stream);
    hipMemsetAsync(deg, 0, N_NODES * sizeof(int), stream);

    k_init_attr<<<(N_NODES * 64 + 255) / 256, 256, 0, stream>>>(node_attr, attr);

    // CSR build (once, reused for all depths)
    k_degree<<<(M_EDGES + 255) / 256, 256, 0, stream>>>(edge_dst, deg);
    k_scan<<<1, 1024, 0, stream>>>(deg, rowptr);
    k_fill<<<(M_EDGES + 255) / 256, 256, 0, stream>>>(edge_dst, deg, eidx);

    k_fp<<<(N_NODES + 15) / 16, 256, 0, stream>>>(attr, W_output, b_output, fp);

    for (int d = 1; d <= DEPTH; d++) {
        k_gather<<<(N_NODES * 64 + 255) / 256, 256, 0, stream>>>(
            attr, edge_attr, edge_src, rowptr, eidx, agg);
        k_inner<<<(N_NODES + 31) / 32, 256, 0, stream>>>(
            attr, agg, W_inner + (size_t)(d - 1) * DIM * DIM,
            b_inner + (size_t)(d - 1) * DIM, attr);
        k_fp<<<(N_NODES + 15) / 16, 256, 0, stream>>>(
            attr, W_output + (size_t)d * DIM * OUT_DIM,
            b_output + (size_t)d * OUT_DIM, fp);
    }
}

// Round 3
// 2198.227 us; speedup vs baseline: 5.5714x; 2.1712x over previous
//
#include <hip/hip_runtime.h>
#include <hip/hip_bf16.h>

#define N_NODES 50000
#define NODE_F  192
#define EDGE_F  64
#define DIM     256
#define OUT_DIM 2048
#define DEPTH   3
#define M_EDGES 800000

typedef short  bf16x8 __attribute__((ext_vector_type(8)));   // 8 bf16 in 4 VGPRs
typedef float  f32x4  __attribute__((ext_vector_type(4)));

__device__ inline short f2bf(float f) {
    unsigned u = __float_as_uint(f);
    unsigned r = (u + 0x7fffu + ((u >> 16) & 1u)) >> 16;
    return (short)r;
}

// ---------------------------------------------------------------------------
// attr = [node_attr | zeros(EDGE_F)]  -> [N, 256], one float4 per thread
// ---------------------------------------------------------------------------
__global__ void k_init_attr(const float* __restrict__ node_attr,
                            float* __restrict__ attr) {
    int i = blockIdx.x * 256 + threadIdx.x;   // float4 index over N*64
    int row = i >> 6, q = i & 63;
    if (row >= N_NODES) return;
    float4 v = make_float4(0.f, 0.f, 0.f, 0.f);
    if (q < NODE_F / 4) v = ((const float4*)node_attr)[row * (NODE_F / 4) + q];
    ((float4*)attr)[i] = v;
}

// ---------------------------------------------------------------------------
// CSR build: degree histogram -> single-block scan -> edge-index fill
// ---------------------------------------------------------------------------
__global__ void k_degree(const int* __restrict__ dst, int* __restrict__ deg) {
    int e = blockIdx.x * 256 + threadIdx.x;
    if (e < M_EDGES) atomicAdd(&deg[dst[e]], 1);
}

__global__ __launch_bounds__(1024) void k_scan(int* __restrict__ deg,
                                               int* __restrict__ rowptr) {
    __shared__ int part[1024];
    int t = threadIdx.x;
    const int CH = (N_NODES + 1023) / 1024;   // 49
    int beg = t * CH, end = min(beg + CH, N_NODES);
    int s = 0;
    for (int i = beg; i < end; i++) s += deg[i];
    part[t] = s;
    __syncthreads();
    for (int off = 1; off < 1024; off <<= 1) {
        int v = (t >= off) ? part[t - off] : 0;
        __syncthreads();
        part[t] += v;
        __syncthreads();
    }
    int run = (t == 0) ? 0 : part[t - 1];
    for (int i = beg; i < end; i++) {
        int d = deg[i];
        rowptr[i] = run;
        deg[i] = run;      // cursor for k_fill
        run += d;
    }
    if (t == 1023) rowptr[N_NODES] = run;
}

__global__ void k_fill(const int* __restrict__ dst, int* __restrict__ cursor,
                       int* __restrict__ eidx) {
    int e = blockIdx.x * 256 + threadIdx.x;
    if (e < M_EDGES) {
        int p = atomicAdd(&cursor[dst[e]], 1);
        eidx[p] = e;
    }
}

// ---------------------------------------------------------------------------
// gather: agg[i] = sum_{e : dst[e]==i} (attr[src[e]] + [0 | edge_attr[e]])
// ---------------------------------------------------------------------------
__global__ __launch_bounds__(256) void k_gather(const float* __restrict__ attr,
                                                const float* __restrict__ edge_attr,
                                                const int* __restrict__ src,
                                                const int* __restrict__ rowptr,
                                                const int* __restrict__ eidx,
                                                float* __restrict__ agg) {
    int gid = blockIdx.x * 256 + threadIdx.x;
    int node = gid >> 6, q = gid & 63;
    if (node >= N_NODES) return;
    int beg = rowptr[node], end = rowptr[node + 1];
    float4 acc = make_float4(0.f, 0.f, 0.f, 0.f);
    const float4* A4 = (const float4*)attr;
    const float4* E4 = (const float4*)edge_attr;
    for (int i = beg; i < end; i++) {
        int e = eidx[i];
        int s = src[e];
        float4 v = A4[(size_t)s * 64 + q];
        if (q >= NODE_F / 4) {
            float4 ea = E4[(size_t)e * (EDGE_F / 4) + (q - NODE_F / 4)];
            v.x += ea.x; v.y += ea.y; v.z += ea.z; v.w += ea.w;
        }
        acc.x += v.x; acc.y += v.y; acc.z += v.z; acc.w += v.w;
    }
    ((float4*)agg)[(size_t)node * 64 + q] = acc;
}

// ---------------------------------------------------------------------------
// inner GEMM: attr_new = (attr + agg) @ W + b, in-place on attr. fp32 vector.
// ---------------------------------------------------------------------------
__global__ __launch_bounds__(256) void k_inner(const float* __restrict__ attr,
                                               const float* __restrict__ agg,
                                               const float* __restrict__ W,
                                               const float* __restrict__ b,
                                               float* __restrict__ out) {
    __shared__ float4 sV[32][64];   // 32 KB
    int tid  = threadIdx.x;
    int row0 = blockIdx.x * 32;

    for (int i = tid; i < 32 * 64; i += 256) {
        int r = i >> 6, q = i & 63;
        int grow = row0 + r;
        float4 v = make_float4(0.f, 0.f, 0.f, 0.f);
        if (grow < N_NODES) {
            float4 a = ((const float4*)attr)[(size_t)grow * 64 + q];
            float4 g = ((const float4*)agg)[(size_t)grow * 64 + q];
            v = make_float4(a.x + g.x, a.y + g.y, a.z + g.z, a.w + g.w);
        }
        sV[r][q] = v;
    }
    __syncthreads();

    int cg = tid & 63;
    int rg = tid >> 6;

    float4 acc[8];
#pragma unroll
    for (int r = 0; r < 8; r++) acc[r] = make_float4(0.f, 0.f, 0.f, 0.f);

    const float4* W4 = (const float4*)W;
    for (int k4 = 0; k4 < 64; k4++) {
        float4 w0 = W4[(size_t)(k4 * 4 + 0) * 64 + cg];
        float4 w1 = W4[(size_t)(k4 * 4 + 1) * 64 + cg];
        float4 w2 = W4[(size_t)(k4 * 4 + 2) * 64 + cg];
        float4 w3 = W4[(size_t)(k4 * 4 + 3) * 64 + cg];
#pragma unroll
        for (int r = 0; r < 8; r++) {
            float4 a = sV[rg * 8 + r][k4];
            acc[r].x += a.x * w0.x + a.y * w1.x + a.z * w2.x + a.w * w3.x;
            acc[r].y += a.x * w0.y + a.y * w1.y + a.z * w2.y + a.w * w3.y;
            acc[r].z += a.x * w0.z + a.y * w1.z + a.z * w2.z + a.w * w3.z;
            acc[r].w += a.x * w0.w + a.y * w1.w + a.z * w2.w + a.w * w3.w;
        }
    }

    float4 bb = ((const float4*)b)[cg];
#pragma unroll
    for (int r = 0; r < 8; r++) {
        int grow = row0 + rg * 8 + r;
        if (grow < N_NODES) {
            float4 o = make_float4(acc[r].x + bb.x, acc[r].y + bb.y,
                                   acc[r].z + bb.z, acc[r].w + bb.w);
            ((float4*)out)[(size_t)grow * 64 + cg] = o;
        }
    }
}

// ---------------------------------------------------------------------------
// W_output swizzle: fp32 [4][256][2048] -> bf16 fragment layout
// Wz[((d*8+ks)*128+T)*64+lane][j] = W[d][ks*32+(lane>>4)*8+j][T*16+(lane&15)]
// ---------------------------------------------------------------------------
__global__ void k_wswz(const float* __restrict__ W, short* __restrict__ Wz) {
    int idx = blockIdx.x * 256 + threadIdx.x;    // 2^18 total
    int lane = idx & 63;
    int T    = (idx >> 6) & 127;
    int ks   = (idx >> 13) & 7;
    int d    = idx >> 16;
    int quad = lane >> 4;
    int m    = lane & 15;
    const float* src = W + ((size_t)(d * 256 + ks * 32 + quad * 8)) * 2048 + T * 16 + m;
    short* dstp = Wz + (size_t)idx * 8;
#pragma unroll
    for (int j = 0; j < 8; j++) dstp[j] = f2bf(src[(size_t)j * 2048]);
}

// ---------------------------------------------------------------------------
// fp contribution via MFMA: fp_part += colsum(softmax(attr @ W + b))
// 16 rows/block, 4 waves x 512 cols, 32 C-frags per lane.
// C/D layout: col = lane&15, row = (lane>>4)*4 + reg.
// ---------------------------------------------------------------------------
__global__ __launch_bounds__(256, 2)
void k_fp_mfma(const float* __restrict__ attr,
               const short* __restrict__ Wz,    // depth-offset applied by host
               const float* __restrict__ bias,
               float* __restrict__ fp_part) {
    __shared__ float sred[4][16];
    int tid  = threadIdx.x;
    int lane = tid & 63;
    int wave = tid >> 6;
    int quad = lane >> 4;
    int m    = lane & 15;
    int row0 = blockIdx.x * 16;
    int col0 = wave * 512;

    f32x4 acc[32];
#pragma unroll
    for (int t = 0; t < 32; t++) acc[t] = (f32x4){0.f, 0.f, 0.f, 0.f};

    const float* arow = attr + (size_t)(row0 + m) * 256 + quad * 8;
    for (int ks = 0; ks < 8; ks++) {
        float4 a0 = *((const float4*)(arow + ks * 32));
        float4 a1 = *((const float4*)(arow + ks * 32 + 4));
        bf16x8 af = { f2bf(a0.x), f2bf(a0.y), f2bf(a0.z), f2bf(a0.w),
                      f2bf(a1.x), f2bf(a1.y), f2bf(a1.z), f2bf(a1.w) };
        const bf16x8* bp = (const bf16x8*)Wz + ((size_t)ks * 128 + wave * 32) * 64 + lane;
#pragma unroll
        for (int t = 0; t < 32; t++) {
            bf16x8 bf = bp[t * 64];
            acc[t] = __builtin_amdgcn_mfma_f32_16x16x32_bf16(af, bf, acc[t], 0, 0, 0);
        }
    }

    // bias (col = col0 + t*16 + m, same for all 4 regs)
#pragma unroll
    for (int t = 0; t < 32; t++) {
        float bb = bias[col0 + t * 16 + m];
        acc[t][0] += bb; acc[t][1] += bb; acc[t][2] += bb; acc[t][3] += bb;
    }

    // row max (rows quad*4+r)
    float mx[4];
#pragma unroll
    for (int r = 0; r < 4; r++) {
        float v = acc[0][r];
#pragma unroll
        for (int t = 1; t < 32; t++) v = fmaxf(v, acc[t][r]);
        mx[r] = v;
    }
#pragma unroll
    for (int off = 1; off < 16; off <<= 1)
#pragma unroll
        for (int r = 0; r < 4; r++) mx[r] = fmaxf(mx[r], __shfl_xor(mx[r], off));
    if (m == 0)
#pragma unroll
        for (int r = 0; r < 4; r++) sred[wave][quad * 4 + r] = mx[r];
    __syncthreads();
#pragma unroll
    for (int r = 0; r < 4; r++) {
        int row = quad * 4 + r;
        mx[r] = fmaxf(fmaxf(sred[0][row], sred[1][row]),
                      fmaxf(sred[2][row], sred[3][row]));
    }
    __syncthreads();

    // exp + row sum
    float ls[4] = {0.f, 0.f, 0.f, 0.f};
#pragma unroll
    for (int t = 0; t < 32; t++) {
#pragma unroll
        for (int r = 0; r < 4; r++) {
            float e = __expf(acc[t][r] - mx[r]);
            acc[t][r] = e;
            ls[r] += e;
        }
    }
#pragma unroll
    for (int off = 1; off < 16; off <<= 1)
#pragma unroll
        for (int r = 0; r < 4; r++) ls[r] += __shfl_xor(ls[r], off);
    if (m == 0)
#pragma unroll
        for (int r = 0; r < 4; r++) sred[wave][quad * 4 + r] = ls[r];
    __syncthreads();
    float rinv[4];
#pragma unroll
    for (int r = 0; r < 4; r++) {
        int row = quad * 4 + r;
        rinv[r] = 1.0f / (sred[0][row] + sred[1][row] + sred[2][row] + sred[3][row]);
    }

    // column sums over 16 rows -> atomics into replica (blockIdx & 63)
    float* dst = fp_part + (size_t)(blockIdx.x & 63) * OUT_DIM;
#pragma unroll
    for (int t = 0; t < 32; t++) {
        float cs = acc[t][0] * rinv[0] + acc[t][1] * rinv[1]
                 + acc[t][2] * rinv[2] + acc[t][3] * rinv[3];
        cs += __shfl_xor(cs, 16);
        cs += __shfl_xor(cs, 32);
        if (quad == (t >> 3))
            atomicAdd(&dst[col0 + t * 16 + m], cs);
    }
}

// ---------------------------------------------------------------------------
__global__ void k_fp_reduce(const float* __restrict__ part, float* __restrict__ fp) {
    int c = blockIdx.x * 256 + threadIdx.x;   // 2048
    float s = 0.f;
#pragma unroll
    for (int r = 0; r < 64; r++) s += part[(size_t)r * OUT_DIM + c];
    fp[c] = s;
}

// ---------------------------------------------------------------------------
extern "C" void kernel_launch(void* const* d_in, const int* in_sizes, int n_in,
                              void* d_out, int out_size, void* d_ws, size_t ws_size,
                              hipStream_t stream) {
    const float* node_attr = (const float*)d_in[0];
    const float* edge_attr = (const float*)d_in[1];
    const int*   edge_src  = (const int*)d_in[2];
    const int*   edge_dst  = (const int*)d_in[3];
    const float* W_inner   = (const float*)d_in[4];
    const float* b_inner   = (const float*)d_in[5];
    const float* W_output  = (const float*)d_in[6];
    const float* b_output  = (const float*)d_in[7];

    float* fp      = (float*)d_out;
    float* attr    = (float*)d_ws;                        // N*256 f32
    float* agg     = attr + (size_t)N_NODES * DIM;        // N*256 f32
    float* fp_part = agg + (size_t)N_NODES * DIM;         // 64*2048 f32
    short* Wz      = (short*)(fp_part + 64 * OUT_DIM);    // 4*2^18*8 bf16 (4 MB)
    int*   deg     = (int*)(Wz + (size_t)4 * 65536 * 8);  // N
    int*   rowptr  = deg + N_NODES;                       // N+1
    int*   eidx    = rowptr + N_NODES + 1;                // M

    hipMemsetAsync(fp_part, 0, 64 * OUT_DIM * sizeof(float), stream);
    hipMemsetAsync(deg, 0, N_NODES * sizeof(int), stream);

    k_init_attr<<<(N_NODES * 64 + 255) / 256, 256, 0, stream>>>(node_attr, attr);

    // CSR build (once, reused for all depths)
    k_degree<<<(M_EDGES + 255) / 256, 256, 0, stream>>>(edge_dst, deg);
    k_scan<<<1, 1024, 0, stream>>>(deg, rowptr);
    k_fill<<<(M_EDGES + 255) / 256, 256, 0, stream>>>(edge_dst, deg, eidx);

    // W_output -> bf16 fragment swizzle (all 4 depths)
    k_wswz<<<1024, 256, 0, stream>>>(W_output, Wz);

    k_fp_mfma<<<N_NODES / 16, 256, 0, stream>>>(attr, Wz, b_output, fp_part);

    for (int d = 1; d <= DEPTH; d++) {
        k_gather<<<(N_NODES * 64 + 255) / 256, 256, 0, stream>>>(
            attr, edge_attr, edge_src, rowptr, eidx, agg);
        k_inner<<<(N_NODES + 31) / 32, 256, 0, stream>>>(
            attr, agg, W_inner + (size_t)(d - 1) * DIM * DIM,
            b_inner + (size_t)(d - 1) * DIM, attr);
        k_fp_mfma<<<N_NODES / 16, 256, 0, stream>>>(
            attr, Wz + (size_t)d * 65536 * 8,
            b_output + (size_t)d * OUT_DIM, fp_part);
    }
    k_fp_reduce<<<OUT_DIM / 256, 256, 0, stream>>>(fp_part, fp);
}

// Round 4
// 2034.289 us; speedup vs baseline: 6.0204x; 1.0806x over previous
//
#include <hip/hip_runtime.h>
#include <hip/hip_bf16.h>

#define N_NODES 50000
#define N_PAD   50016          // padded to 32-row blocks for k_fp_mfma
#define NODE_F  192
#define EDGE_F  64
#define DIM     256
#define OUT_DIM 2048
#define DEPTH   3
#define M_EDGES 800000

typedef short  bf16x8 __attribute__((ext_vector_type(8)));   // 8 bf16 in 4 VGPRs
typedef float  f32x4  __attribute__((ext_vector_type(4)));

__device__ inline short f2bf(float f) {
    unsigned u = __float_as_uint(f);
    unsigned r = (u + 0x7fffu + ((u >> 16) & 1u)) >> 16;
    return (short)r;
}

// ---------------------------------------------------------------------------
// attr = [node_attr | zeros(EDGE_F)] -> [N,256] fp32, plus bf16 mirror
// (mirror padded to N_PAD rows with zeros; ws is poison-filled each call)
// ---------------------------------------------------------------------------
__global__ void k_init_attr(const float* __restrict__ node_attr,
                            float* __restrict__ attr,
                            short* __restrict__ attr_bf) {
    int i = blockIdx.x * 256 + threadIdx.x;   // float4/short4 slot over N_PAD*64
    int row = i >> 6, q = i & 63;
    if (row >= N_PAD) return;
    float4 v = make_float4(0.f, 0.f, 0.f, 0.f);
    if (row < N_NODES && q < NODE_F / 4)
        v = ((const float4*)node_attr)[row * (NODE_F / 4) + q];
    if (row < N_NODES) ((float4*)attr)[i] = v;
    short4 s; s.x = f2bf(v.x); s.y = f2bf(v.y); s.z = f2bf(v.z); s.w = f2bf(v.w);
    ((short4*)attr_bf)[i] = s;
}

// ---------------------------------------------------------------------------
// CSR build: degree histogram -> single-block scan -> edge-index fill
// ---------------------------------------------------------------------------
__global__ void k_degree(const int* __restrict__ dst, int* __restrict__ deg) {
    int e = blockIdx.x * 256 + threadIdx.x;
    if (e < M_EDGES) atomicAdd(&deg[dst[e]], 1);
}

__global__ __launch_bounds__(1024) void k_scan(int* __restrict__ deg,
                                               int* __restrict__ rowptr) {
    __shared__ int part[1024];
    int t = threadIdx.x;
    const int CH = (N_NODES + 1023) / 1024;   // 49
    int beg = t * CH, end = min(beg + CH, N_NODES);
    int s = 0;
    for (int i = beg; i < end; i++) s += deg[i];
    part[t] = s;
    __syncthreads();
    for (int off = 1; off < 1024; off <<= 1) {
        int v = (t >= off) ? part[t - off] : 0;
        __syncthreads();
        part[t] += v;
        __syncthreads();
    }
    int run = (t == 0) ? 0 : part[t - 1];
    for (int i = beg; i < end; i++) {
        int d = deg[i];
        rowptr[i] = run;
        deg[i] = run;      // cursor for k_fill
        run += d;
    }
    if (t == 1023) rowptr[N_NODES] = run;
}

__global__ void k_fill(const int* __restrict__ dst, int* __restrict__ cursor,
                       int* __restrict__ eidx) {
    int e = blockIdx.x * 256 + threadIdx.x;
    if (e < M_EDGES) {
        int p = atomicAdd(&cursor[dst[e]], 1);
        eidx[p] = e;
    }
}

// ---------------------------------------------------------------------------
// gather: agg[i] = sum_{e : dst[e]==i} (attr[src[e]] + [0 | edge_attr[e]])
// ---------------------------------------------------------------------------
__global__ __launch_bounds__(256) void k_gather(const float* __restrict__ attr,
                                                const float* __restrict__ edge_attr,
                                                const int* __restrict__ src,
                                                const int* __restrict__ rowptr,
                                                const int* __restrict__ eidx,
                                                float* __restrict__ agg) {
    int gid = blockIdx.x * 256 + threadIdx.x;
    int node = gid >> 6, q = gid & 63;
    if (node >= N_NODES) return;
    int beg = rowptr[node], end = rowptr[node + 1];
    float4 acc = make_float4(0.f, 0.f, 0.f, 0.f);
    const float4* A4 = (const float4*)attr;
    const float4* E4 = (const float4*)edge_attr;
    for (int i = beg; i < end; i++) {
        int e = eidx[i];
        int s = src[e];
        float4 v = A4[(size_t)s * 64 + q];
        if (q >= NODE_F / 4) {
            float4 ea = E4[(size_t)e * (EDGE_F / 4) + (q - NODE_F / 4)];
            v.x += ea.x; v.y += ea.y; v.z += ea.z; v.w += ea.w;
        }
        acc.x += v.x; acc.y += v.y; acc.z += v.z; acc.w += v.w;
    }
    ((float4*)agg)[(size_t)node * 64 + q] = acc;
}

// ---------------------------------------------------------------------------
// inner GEMM: attr_new = (attr + agg) @ W + b, in-place on attr (fp32 vector),
// also writes the bf16 mirror used by k_fp_mfma.
// ---------------------------------------------------------------------------
__global__ __launch_bounds__(256) void k_inner(const float* __restrict__ attr,
                                               const float* __restrict__ agg,
                                               const float* __restrict__ W,
                                               const float* __restrict__ b,
                                               float* __restrict__ out,
                                               short* __restrict__ out_bf) {
    __shared__ float4 sV[32][64];   // 32 KB
    int tid  = threadIdx.x;
    int row0 = blockIdx.x * 32;

    for (int i = tid; i < 32 * 64; i += 256) {
        int r = i >> 6, q = i & 63;
        int grow = row0 + r;
        float4 v = make_float4(0.f, 0.f, 0.f, 0.f);
        if (grow < N_NODES) {
            float4 a = ((const float4*)attr)[(size_t)grow * 64 + q];
            float4 g = ((const float4*)agg)[(size_t)grow * 64 + q];
            v = make_float4(a.x + g.x, a.y + g.y, a.z + g.z, a.w + g.w);
        }
        sV[r][q] = v;
    }
    __syncthreads();

    int cg = tid & 63;
    int rg = tid >> 6;

    float4 acc[8];
#pragma unroll
    for (int r = 0; r < 8; r++) acc[r] = make_float4(0.f, 0.f, 0.f, 0.f);

    const float4* W4 = (const float4*)W;
    for (int k4 = 0; k4 < 64; k4++) {
        float4 w0 = W4[(size_t)(k4 * 4 + 0) * 64 + cg];
        float4 w1 = W4[(size_t)(k4 * 4 + 1) * 64 + cg];
        float4 w2 = W4[(size_t)(k4 * 4 + 2) * 64 + cg];
        float4 w3 = W4[(size_t)(k4 * 4 + 3) * 64 + cg];
#pragma unroll
        for (int r = 0; r < 8; r++) {
            float4 a = sV[rg * 8 + r][k4];
            acc[r].x += a.x * w0.x + a.y * w1.x + a.z * w2.x + a.w * w3.x;
            acc[r].y += a.x * w0.y + a.y * w1.y + a.z * w2.y + a.w * w3.y;
            acc[r].z += a.x * w0.z + a.y * w1.z + a.z * w2.z + a.w * w3.z;
            acc[r].w += a.x * w0.w + a.y * w1.w + a.z * w2.w + a.w * w3.w;
        }
    }

    float4 bb = ((const float4*)b)[cg];
#pragma unroll
    for (int r = 0; r < 8; r++) {
        int grow = row0 + rg * 8 + r;
        if (grow < N_NODES) {
            float4 o = make_float4(acc[r].x + bb.x, acc[r].y + bb.y,
                                   acc[r].z + bb.z, acc[r].w + bb.w);
            ((float4*)out)[(size_t)grow * 64 + cg] = o;
            short4 s; s.x = f2bf(o.x); s.y = f2bf(o.y); s.z = f2bf(o.z); s.w = f2bf(o.w);
            ((short4*)out_bf)[(size_t)grow * 64 + cg] = s;
        }
    }
}

// ---------------------------------------------------------------------------
// W_output swizzle: fp32 [4][256][2048] -> bf16 fragment layout
// Wz[((d*8+ks)*128+T)*64+lane][j] = W[d][ks*32+(lane>>4)*8+j][T*16+(lane&15)]
// ---------------------------------------------------------------------------
__global__ void k_wswz(const float* __restrict__ W, short* __restrict__ Wz) {
    int idx = blockIdx.x * 256 + threadIdx.x;    // 2^18 total
    int lane = idx & 63;
    int T    = (idx >> 6) & 127;
    int ks   = (idx >> 13) & 7;
    int d    = idx >> 16;
    int quad = lane >> 4;
    int m    = lane & 15;
    const float* src = W + ((size_t)(d * 256 + ks * 32 + quad * 8)) * 2048 + T * 16 + m;
    short* dstp = Wz + (size_t)idx * 8;
#pragma unroll
    for (int j = 0; j < 8; j++) dstp[j] = f2bf(src[(size_t)j * 2048]);
}

// ---------------------------------------------------------------------------
// fp contribution via MFMA: fp_part += colsum(softmax(attr @ W + b))
// 32 rows/block, 1024 thr = 16 waves; wave = 32 rows x 128 cols
// (2 row-tiles x 8 col-tiles = 16 C-frags = 64 acc VGPRs -> 4 waves/SIMD).
// C/D layout: col = lane&15, row = (lane>>4)*4 + reg.
// ---------------------------------------------------------------------------
__global__ __launch_bounds__(1024)
void k_fp_mfma(const short* __restrict__ attr_bf,
               const short* __restrict__ Wz,    // depth offset applied by host
               const float* __restrict__ bias,
               float* __restrict__ fp_part) {
    __shared__ float sred[32][17];
    __shared__ float sfinm[32];
    __shared__ float sfinl[32];
    int tid  = threadIdx.x;
    int lane = tid & 63;
    int wave = tid >> 6;          // 0..15
    int quad = lane >> 4;
    int m    = lane & 15;
    int row0 = blockIdx.x * 32;

    f32x4 acc0[8], acc1[8];
#pragma unroll
    for (int t = 0; t < 8; t++) {
        acc0[t] = (f32x4){0.f, 0.f, 0.f, 0.f};
        acc1[t] = (f32x4){0.f, 0.f, 0.f, 0.f};
    }

    const short* a0p = attr_bf + (size_t)(row0 + m) * 256 + quad * 8;
    const short* a1p = a0p + 16 * 256;
    for (int ks = 0; ks < 8; ks++) {
        bf16x8 af0 = *(const bf16x8*)(a0p + ks * 32);
        bf16x8 af1 = *(const bf16x8*)(a1p + ks * 32);
        const bf16x8* bp = (const bf16x8*)Wz + ((size_t)ks * 128 + wave * 8) * 64 + lane;
#pragma unroll
        for (int t = 0; t < 8; t++) {
            bf16x8 bf = bp[t * 64];
            acc0[t] = __builtin_amdgcn_mfma_f32_16x16x32_bf16(af0, bf, acc0[t], 0, 0, 0);
            acc1[t] = __builtin_amdgcn_mfma_f32_16x16x32_bf16(af1, bf, acc1[t], 0, 0, 0);
        }
    }

    // bias (col = (wave*8+t)*16 + m)
#pragma unroll
    for (int t = 0; t < 8; t++) {
        float bb = bias[(wave * 8 + t) * 16 + m];
        acc0[t][0] += bb; acc0[t][1] += bb; acc0[t][2] += bb; acc0[t][3] += bb;
        acc1[t][0] += bb; acc1[t][1] += bb; acc1[t][2] += bb; acc1[t][3] += bb;
    }

    // ---- row max: per-lane over tiles, shuffle over m, LDS across waves ----
    float mx0[4], mx1[4];
#pragma unroll
    for (int r = 0; r < 4; r++) {
        float v0 = acc0[0][r], v1 = acc1[0][r];
#pragma unroll
        for (int t = 1; t < 8; t++) { v0 = fmaxf(v0, acc0[t][r]); v1 = fmaxf(v1, acc1[t][r]); }
        mx0[r] = v0; mx1[r] = v1;
    }
#pragma unroll
    for (int off = 1; off < 16; off <<= 1)
#pragma unroll
        for (int r = 0; r < 4; r++) {
            mx0[r] = fmaxf(mx0[r], __shfl_xor(mx0[r], off));
            mx1[r] = fmaxf(mx1[r], __shfl_xor(mx1[r], off));
        }
    if (m == 0)
#pragma unroll
        for (int r = 0; r < 4; r++) {
            sred[quad * 4 + r][wave]      = mx0[r];
            sred[16 + quad * 4 + r][wave] = mx1[r];
        }
    __syncthreads();
    if (tid < 32) {
        float v = sred[tid][0];
#pragma unroll
        for (int w = 1; w < 16; w++) v = fmaxf(v, sred[tid][w]);
        sfinm[tid] = v;
    }
    __syncthreads();
#pragma unroll
    for (int r = 0; r < 4; r++) { mx0[r] = sfinm[quad * 4 + r]; mx1[r] = sfinm[16 + quad * 4 + r]; }

    // ---- exp + row sum ----
    float ls0[4] = {0.f, 0.f, 0.f, 0.f}, ls1[4] = {0.f, 0.f, 0.f, 0.f};
#pragma unroll
    for (int t = 0; t < 8; t++) {
#pragma unroll
        for (int r = 0; r < 4; r++) {
            float e0 = __expf(acc0[t][r] - mx0[r]);
            float e1 = __expf(acc1[t][r] - mx1[r]);
            acc0[t][r] = e0; acc1[t][r] = e1;
            ls0[r] += e0; ls1[r] += e1;
        }
    }
#pragma unroll
    for (int off = 1; off < 16; off <<= 1)
#pragma unroll
        for (int r = 0; r < 4; r++) {
            ls0[r] += __shfl_xor(ls0[r], off);
            ls1[r] += __shfl_xor(ls1[r], off);
        }
    if (m == 0)
#pragma unroll
        for (int r = 0; r < 4; r++) {
            sred[quad * 4 + r][wave]      = ls0[r];
            sred[16 + quad * 4 + r][wave] = ls1[r];
        }
    __syncthreads();
    if (tid < 32) {
        float v = 0.f;
#pragma unroll
        for (int w = 0; w < 16; w++) v += sred[tid][w];
        sfinl[tid] = v;
    }
    __syncthreads();

    float rinv0[4], rinv1[4];
#pragma unroll
    for (int r = 0; r < 4; r++) {
        int ra = quad * 4 + r, rb = 16 + quad * 4 + r;
        rinv0[r] = (row0 + ra < N_NODES) ? 1.0f / sfinl[ra] : 0.0f;
        rinv1[r] = (row0 + rb < N_NODES) ? 1.0f / sfinl[rb] : 0.0f;
    }

    // ---- column sums over 32 rows -> atomics into replica ----
    float* dst = fp_part + (size_t)(blockIdx.x & 63) * OUT_DIM;
#pragma unroll
    for (int t = 0; t < 8; t++) {
        float cs = acc0[t][0] * rinv0[0] + acc0[t][1] * rinv0[1]
                 + acc0[t][2] * rinv0[2] + acc0[t][3] * rinv0[3]
                 + acc1[t][0] * rinv1[0] + acc1[t][1] * rinv1[1]
                 + acc1[t][2] * rinv1[2] + acc1[t][3] * rinv1[3];
        cs += __shfl_xor(cs, 16);
        cs += __shfl_xor(cs, 32);
        if (quad == 0)
            atomicAdd(&dst[(wave * 8 + t) * 16 + m], cs);
    }
}

// ---------------------------------------------------------------------------
__global__ void k_fp_reduce(const float* __restrict__ part, float* __restrict__ fp) {
    int c = blockIdx.x * 256 + threadIdx.x;   // 2048
    float s = 0.f;
#pragma unroll
    for (int r = 0; r < 64; r++) s += part[(size_t)r * OUT_DIM + c];
    fp[c] = s;
}

// ---------------------------------------------------------------------------
extern "C" void kernel_launch(void* const* d_in, const int* in_sizes, int n_in,
                              void* d_out, int out_size, void* d_ws, size_t ws_size,
                              hipStream_t stream) {
    const float* node_attr = (const float*)d_in[0];
    const float* edge_attr = (const float*)d_in[1];
    const int*   edge_src  = (const int*)d_in[2];
    const int*   edge_dst  = (const int*)d_in[3];
    const float* W_inner   = (const float*)d_in[4];
    const float* b_inner   = (const float*)d_in[5];
    const float* W_output  = (const float*)d_in[6];
    const float* b_output  = (const float*)d_in[7];

    float* fp      = (float*)d_out;
    float* attr    = (float*)d_ws;                        // N*256 f32
    float* agg     = attr + (size_t)N_NODES * DIM;        // N*256 f32
    float* fp_part = agg + (size_t)N_NODES * DIM;         // 64*2048 f32
    short* Wz      = (short*)(fp_part + 64 * OUT_DIM);    // 4*2^18*8 bf16 (4 MB)
    int*   deg     = (int*)(Wz + (size_t)4 * 65536 * 8);  // N
    int*   rowptr  = deg + N_NODES;                       // N+1
    int*   eidx    = rowptr + N_NODES + 1;                // M
    short* attr_bf = (short*)(eidx + M_EDGES);            // N_PAD*256 bf16 (25.6 MB)

    hipMemsetAsync(fp_part, 0, 64 * OUT_DIM * sizeof(float), stream);
    hipMemsetAsync(deg, 0, N_NODES * sizeof(int), stream);

    k_init_attr<<<(N_PAD * 64 + 255) / 256, 256, 0, stream>>>(node_attr, attr, attr_bf);

    // CSR build (once, reused for all depths)
    k_degree<<<(M_EDGES + 255) / 256, 256, 0, stream>>>(edge_dst, deg);
    k_scan<<<1, 1024, 0, stream>>>(deg, rowptr);
    k_fill<<<(M_EDGES + 255) / 256, 256, 0, stream>>>(edge_dst, deg, eidx);

    // W_output -> bf16 fragment swizzle (all 4 depths)
    k_wswz<<<1024, 256, 0, stream>>>(W_output, Wz);

    k_fp_mfma<<<N_PAD / 32, 1024, 0, stream>>>(attr_bf, Wz, b_output, fp_part);

    for (int d = 1; d <= DEPTH; d++) {
        k_gather<<<(N_NODES * 64 + 255) / 256, 256, 0, stream>>>(
            attr, edge_attr, edge_src, rowptr, eidx, agg);
        k_inner<<<(N_NODES + 31) / 32, 256, 0, stream>>>(
            attr, agg, W_inner + (size_t)(d - 1) * DIM * DIM,
            b_inner + (size_t)(d - 1) * DIM, attr, attr_bf);
        k_fp_mfma<<<N_PAD / 32, 1024, 0, stream>>>(
            attr_bf, Wz + (size_t)d * 65536 * 8,
            b_output + (size_t)d * OUT_DIM, fp_part);
    }
    k_fp_reduce<<<OUT_DIM / 256, 256, 0, stream>>>(fp_part, fp);
}

// Round 5
// 1859.326 us; speedup vs baseline: 6.5870x; 1.0941x over previous
//
#include <hip/hip_runtime.h>
#include <hip/hip_bf16.h>

#define N_NODES 50000
#define N_PAD   50016          // padded to 32-row blocks for k_fp_mfma
#define NODE_F  192
#define EDGE_F  64
#define DIM     256
#define OUT_DIM 2048
#define DEPTH   3
#define M_EDGES 800000

typedef short  bf16x8 __attribute__((ext_vector_type(8)));   // 8 bf16 in 4 VGPRs
typedef float  f32x4  __attribute__((ext_vector_type(4)));

__device__ inline short f2bf(float f) {
    unsigned u = __float_as_uint(f);
    unsigned r = (u + 0x7fffu + ((u >> 16) & 1u)) >> 16;
    return (short)r;
}

// ---------------------------------------------------------------------------
// attr = [node_attr | zeros(EDGE_F)] -> [N,256] fp32, plus bf16 mirror
// ---------------------------------------------------------------------------
__global__ void k_init_attr(const float* __restrict__ node_attr,
                            float* __restrict__ attr,
                            short* __restrict__ attr_bf) {
    int i = blockIdx.x * 256 + threadIdx.x;   // float4/short4 slot over N_PAD*64
    int row = i >> 6, q = i & 63;
    if (row >= N_PAD) return;
    float4 v = make_float4(0.f, 0.f, 0.f, 0.f);
    if (row < N_NODES && q < NODE_F / 4)
        v = ((const float4*)node_attr)[row * (NODE_F / 4) + q];
    if (row < N_NODES) ((float4*)attr)[i] = v;
    short4 s; s.x = f2bf(v.x); s.y = f2bf(v.y); s.z = f2bf(v.z); s.w = f2bf(v.w);
    ((short4*)attr_bf)[i] = s;
}

// ---------------------------------------------------------------------------
// CSR build: degree histogram -> single-block scan -> edge-index fill
// ---------------------------------------------------------------------------
__global__ void k_degree(const int* __restrict__ dst, int* __restrict__ deg) {
    int e = blockIdx.x * 256 + threadIdx.x;
    if (e < M_EDGES) atomicAdd(&deg[dst[e]], 1);
}

__global__ __launch_bounds__(1024) void k_scan(int* __restrict__ deg,
                                               int* __restrict__ rowptr) {
    __shared__ int part[1024];
    int t = threadIdx.x;
    const int CH = (N_NODES + 1023) / 1024;   // 49
    int beg = t * CH, end = min(beg + CH, N_NODES);
    int s = 0;
    for (int i = beg; i < end; i++) s += deg[i];
    part[t] = s;
    __syncthreads();
    for (int off = 1; off < 1024; off <<= 1) {
        int v = (t >= off) ? part[t - off] : 0;
        __syncthreads();
        part[t] += v;
        __syncthreads();
    }
    int run = (t == 0) ? 0 : part[t - 1];
    for (int i = beg; i < end; i++) {
        int d = deg[i];
        rowptr[i] = run;
        deg[i] = run;      // cursor for k_fill
        run += d;
    }
    if (t == 1023) rowptr[N_NODES] = run;
}

// fill: eidx (edge id, dst-sorted) and srcs (source node, dst-sorted)
__global__ void k_fill(const int* __restrict__ dst, const int* __restrict__ src,
                       int* __restrict__ cursor,
                       int* __restrict__ eidx, int* __restrict__ srcs) {
    int e = blockIdx.x * 256 + threadIdx.x;
    if (e < M_EDGES) {
        int p = atomicAdd(&cursor[dst[e]], 1);
        eidx[p] = e;
        srcs[p] = src[e];
    }
}

// ---------------------------------------------------------------------------
// esum[i] = sum_{e : dst[e]==i} edge_attr[e]   (depth-invariant, [N,64] f32)
// 16 threads per node, one float4 lane each.
// ---------------------------------------------------------------------------
__global__ __launch_bounds__(256) void k_esum(const float* __restrict__ edge_attr,
                                              const int* __restrict__ rowptr,
                                              const int* __restrict__ eidx,
                                              float* __restrict__ esum) {
    int gid = blockIdx.x * 256 + threadIdx.x;   // over N*16
    int node = gid >> 4, q = gid & 15;
    if (node >= N_NODES) return;
    int beg = rowptr[node], end = rowptr[node + 1];
    float4 acc = make_float4(0.f, 0.f, 0.f, 0.f);
    const float4* E4 = (const float4*)edge_attr;
    for (int i = beg; i < end; i++) {
        int e = eidx[i];
        float4 v = E4[(size_t)e * 16 + q];
        acc.x += v.x; acc.y += v.y; acc.z += v.z; acc.w += v.w;
    }
    ((float4*)esum)[(size_t)node * 16 + q] = acc;
}

// ---------------------------------------------------------------------------
// gather: agg[i] = esum_pad[i] + sum_{e : dst[e]==i} attr[srcs]
// one wave (64 lanes x float4) per node; srcs is dst-sorted (sequential).
// ---------------------------------------------------------------------------
__global__ __launch_bounds__(256) void k_gather(const float* __restrict__ attr,
                                                const int* __restrict__ rowptr,
                                                const int* __restrict__ srcs,
                                                const float* __restrict__ esum,
                                                float* __restrict__ agg) {
    int gid = blockIdx.x * 256 + threadIdx.x;
    int node = gid >> 6, q = gid & 63;
    if (node >= N_NODES) return;
    int beg = rowptr[node], end = rowptr[node + 1];
    float4 acc = make_float4(0.f, 0.f, 0.f, 0.f);
    if (q >= NODE_F / 4)
        acc = ((const float4*)esum)[(size_t)node * 16 + (q - NODE_F / 4)];
    const float4* A4 = (const float4*)attr;
    for (int i = beg; i < end; i++) {
        int s = srcs[i];                 // wave-uniform sequential load
        float4 v = A4[(size_t)s * 64 + q];
        acc.x += v.x; acc.y += v.y; acc.z += v.z; acc.w += v.w;
    }
    ((float4*)agg)[(size_t)node * 64 + q] = acc;
}

// ---------------------------------------------------------------------------
// inner GEMM: attr_new = (attr + agg) @ W + b, in-place on attr (fp32 vector),
// also writes the bf16 mirror used by k_fp_mfma.
// ---------------------------------------------------------------------------
__global__ __launch_bounds__(256) void k_inner(const float* __restrict__ attr,
                                               const float* __restrict__ agg,
                                               const float* __restrict__ W,
                                               const float* __restrict__ b,
                                               float* __restrict__ out,
                                               short* __restrict__ out_bf) {
    __shared__ float4 sV[32][64];   // 32 KB
    int tid  = threadIdx.x;
    int row0 = blockIdx.x * 32;

    for (int i = tid; i < 32 * 64; i += 256) {
        int r = i >> 6, q = i & 63;
        int grow = row0 + r;
        float4 v = make_float4(0.f, 0.f, 0.f, 0.f);
        if (grow < N_NODES) {
            float4 a = ((const float4*)attr)[(size_t)grow * 64 + q];
            float4 g = ((const float4*)agg)[(size_t)grow * 64 + q];
            v = make_float4(a.x + g.x, a.y + g.y, a.z + g.z, a.w + g.w);
        }
        sV[r][q] = v;
    }
    __syncthreads();

    int cg = tid & 63;
    int rg = tid >> 6;

    float4 acc[8];
#pragma unroll
    for (int r = 0; r < 8; r++) acc[r] = make_float4(0.f, 0.f, 0.f, 0.f);

    const float4* W4 = (const float4*)W;
    for (int k4 = 0; k4 < 64; k4++) {
        float4 w0 = W4[(size_t)(k4 * 4 + 0) * 64 + cg];
        float4 w1 = W4[(size_t)(k4 * 4 + 1) * 64 + cg];
        float4 w2 = W4[(size_t)(k4 * 4 + 2) * 64 + cg];
        float4 w3 = W4[(size_t)(k4 * 4 + 3) * 64 + cg];
#pragma unroll
        for (int r = 0; r < 8; r++) {
            float4 a = sV[rg * 8 + r][k4];
            acc[r].x += a.x * w0.x + a.y * w1.x + a.z * w2.x + a.w * w3.x;
            acc[r].y += a.x * w0.y + a.y * w1.y + a.z * w2.y + a.w * w3.y;
            acc[r].z += a.x * w0.z + a.y * w1.z + a.z * w2.z + a.w * w3.z;
            acc[r].w += a.x * w0.w + a.y * w1.w + a.z * w2.w + a.w * w3.w;
        }
    }

    float4 bb = ((const float4*)b)[cg];
#pragma unroll
    for (int r = 0; r < 8; r++) {
        int grow = row0 + rg * 8 + r;
        if (grow < N_NODES) {
            float4 o = make_float4(acc[r].x + bb.x, acc[r].y + bb.y,
                                   acc[r].z + bb.z, acc[r].w + bb.w);
            ((float4*)out)[(size_t)grow * 64 + cg] = o;
            short4 s; s.x = f2bf(o.x); s.y = f2bf(o.y); s.z = f2bf(o.z); s.w = f2bf(o.w);
            ((short4*)out_bf)[(size_t)grow * 64 + cg] = s;
        }
    }
}

// ---------------------------------------------------------------------------
// W_output swizzle: fp32 [4][256][2048] -> bf16 fragment layout
// ---------------------------------------------------------------------------
__global__ void k_wswz(const float* __restrict__ W, short* __restrict__ Wz) {
    int idx = blockIdx.x * 256 + threadIdx.x;    // 2^18 total
    int lane = idx & 63;
    int T    = (idx >> 6) & 127;
    int ks   = (idx >> 13) & 7;
    int d    = idx >> 16;
    int quad = lane >> 4;
    int m    = lane & 15;
    const float* src = W + ((size_t)(d * 256 + ks * 32 + quad * 8)) * 2048 + T * 16 + m;
    short* dstp = Wz + (size_t)idx * 8;
#pragma unroll
    for (int j = 0; j < 8; j++) dstp[j] = f2bf(src[(size_t)j * 2048]);
}

// ---------------------------------------------------------------------------
// fp contribution via MFMA: fp_part += colsum(softmax(attr @ W + b))
// 32 rows/block, 1024 thr = 16 waves; wave = 32 rows x 128 cols.
// C/D layout: col = lane&15, row = (lane>>4)*4 + reg.
// ---------------------------------------------------------------------------
__global__ __launch_bounds__(1024)
void k_fp_mfma(const short* __restrict__ attr_bf,
               const short* __restrict__ Wz,    // depth offset applied by host
               const float* __restrict__ bias,
               float* __restrict__ fp_part) {
    __shared__ float sred[32][17];
    __shared__ float sfinm[32];
    __shared__ float sfinl[32];
    int tid  = threadIdx.x;
    int lane = tid & 63;
    int wave = tid >> 6;          // 0..15
    int quad = lane >> 4;
    int m    = lane & 15;
    int row0 = blockIdx.x * 32;

    f32x4 acc0[8], acc1[8];
#pragma unroll
    for (int t = 0; t < 8; t++) {
        acc0[t] = (f32x4){0.f, 0.f, 0.f, 0.f};
        acc1[t] = (f32x4){0.f, 0.f, 0.f, 0.f};
    }

    const short* a0p = attr_bf + (size_t)(row0 + m) * 256 + quad * 8;
    const short* a1p = a0p + 16 * 256;
    for (int ks = 0; ks < 8; ks++) {
        bf16x8 af0 = *(const bf16x8*)(a0p + ks * 32);
        bf16x8 af1 = *(const bf16x8*)(a1p + ks * 32);
        const bf16x8* bp = (const bf16x8*)Wz + ((size_t)ks * 128 + wave * 8) * 64 + lane;
#pragma unroll
        for (int t = 0; t < 8; t++) {
            bf16x8 bf = bp[t * 64];
            acc0[t] = __builtin_amdgcn_mfma_f32_16x16x32_bf16(af0, bf, acc0[t], 0, 0, 0);
            acc1[t] = __builtin_amdgcn_mfma_f32_16x16x32_bf16(af1, bf, acc1[t], 0, 0, 0);
        }
    }

    // bias (col = (wave*8+t)*16 + m)
#pragma unroll
    for (int t = 0; t < 8; t++) {
        float bb = bias[(wave * 8 + t) * 16 + m];
        acc0[t][0] += bb; acc0[t][1] += bb; acc0[t][2] += bb; acc0[t][3] += bb;
        acc1[t][0] += bb; acc1[t][1] += bb; acc1[t][2] += bb; acc1[t][3] += bb;
    }

    // ---- row max ----
    float mx0[4], mx1[4];
#pragma unroll
    for (int r = 0; r < 4; r++) {
        float v0 = acc0[0][r], v1 = acc1[0][r];
#pragma unroll
        for (int t = 1; t < 8; t++) { v0 = fmaxf(v0, acc0[t][r]); v1 = fmaxf(v1, acc1[t][r]); }
        mx0[r] = v0; mx1[r] = v1;
    }
#pragma unroll
    for (int off = 1; off < 16; off <<= 1)
#pragma unroll
        for (int r = 0; r < 4; r++) {
            mx0[r] = fmaxf(mx0[r], __shfl_xor(mx0[r], off));
            mx1[r] = fmaxf(mx1[r], __shfl_xor(mx1[r], off));
        }
    if (m == 0)
#pragma unroll
        for (int r = 0; r < 4; r++) {
            sred[quad * 4 + r][wave]      = mx0[r];
            sred[16 + quad * 4 + r][wave] = mx1[r];
        }
    __syncthreads();
    if (tid < 32) {
        float v = sred[tid][0];
#pragma unroll
        for (int w = 1; w < 16; w++) v = fmaxf(v, sred[tid][w]);
        sfinm[tid] = v;
    }
    __syncthreads();
#pragma unroll
    for (int r = 0; r < 4; r++) { mx0[r] = sfinm[quad * 4 + r]; mx1[r] = sfinm[16 + quad * 4 + r]; }

    // ---- exp + row sum ----
    float ls0[4] = {0.f, 0.f, 0.f, 0.f}, ls1[4] = {0.f, 0.f, 0.f, 0.f};
#pragma unroll
    for (int t = 0; t < 8; t++) {
#pragma unroll
        for (int r = 0; r < 4; r++) {
            float e0 = __expf(acc0[t][r] - mx0[r]);
            float e1 = __expf(acc1[t][r] - mx1[r]);
            acc0[t][r] = e0; acc1[t][r] = e1;
            ls0[r] += e0; ls1[r] += e1;
        }
    }
#pragma unroll
    for (int off = 1; off < 16; off <<= 1)
#pragma unroll
        for (int r = 0; r < 4; r++) {
            ls0[r] += __shfl_xor(ls0[r], off);
            ls1[r] += __shfl_xor(ls1[r], off);
        }
    if (m == 0)
#pragma unroll
        for (int r = 0; r < 4; r++) {
            sred[quad * 4 + r][wave]      = ls0[r];
            sred[16 + quad * 4 + r][wave] = ls1[r];
        }
    __syncthreads();
    if (tid < 32) {
        float v = 0.f;
#pragma unroll
        for (int w = 0; w < 16; w++) v += sred[tid][w];
        sfinl[tid] = v;
    }
    __syncthreads();

    float rinv0[4], rinv1[4];
#pragma unroll
    for (int r = 0; r < 4; r++) {
        int ra = quad * 4 + r, rb = 16 + quad * 4 + r;
        rinv0[r] = (row0 + ra < N_NODES) ? 1.0f / sfinl[ra] : 0.0f;
        rinv1[r] = (row0 + rb < N_NODES) ? 1.0f / sfinl[rb] : 0.0f;
    }

    // ---- column sums over 32 rows -> atomics into replica ----
    float* dst = fp_part + (size_t)(blockIdx.x & 63) * OUT_DIM;
#pragma unroll
    for (int t = 0; t < 8; t++) {
        float cs = acc0[t][0] * rinv0[0] + acc0[t][1] * rinv0[1]
                 + acc0[t][2] * rinv0[2] + acc0[t][3] * rinv0[3]
                 + acc1[t][0] * rinv1[0] + acc1[t][1] * rinv1[1]
                 + acc1[t][2] * rinv1[2] + acc1[t][3] * rinv1[3];
        cs += __shfl_xor(cs, 16);
        cs += __shfl_xor(cs, 32);
        if (quad == 0)
            atomicAdd(&dst[(wave * 8 + t) * 16 + m], cs);
    }
}

// ---------------------------------------------------------------------------
__global__ void k_fp_reduce(const float* __restrict__ part, float* __restrict__ fp) {
    int c = blockIdx.x * 256 + threadIdx.x;   // 2048
    float s = 0.f;
#pragma unroll
    for (int r = 0; r < 64; r++) s += part[(size_t)r * OUT_DIM + c];
    fp[c] = s;
}

// ---------------------------------------------------------------------------
extern "C" void kernel_launch(void* const* d_in, const int* in_sizes, int n_in,
                              void* d_out, int out_size, void* d_ws, size_t ws_size,
                              hipStream_t stream) {
    const float* node_attr = (const float*)d_in[0];
    const float* edge_attr = (const float*)d_in[1];
    const int*   edge_src  = (const int*)d_in[2];
    const int*   edge_dst  = (const int*)d_in[3];
    const float* W_inner   = (const float*)d_in[4];
    const float* b_inner   = (const float*)d_in[5];
    const float* W_output  = (const float*)d_in[6];
    const float* b_output  = (const float*)d_in[7];

    float* fp      = (float*)d_out;
    float* attr    = (float*)d_ws;                        // N*256 f32
    float* agg     = attr + (size_t)N_NODES * DIM;        // N*256 f32
    float* fp_part = agg + (size_t)N_NODES * DIM;         // 64*2048 f32
    short* Wz      = (short*)(fp_part + 64 * OUT_DIM);    // 4*2^18*8 bf16 (4 MB)
    int*   deg     = (int*)(Wz + (size_t)4 * 65536 * 8);  // N
    int*   rowptr  = deg + N_NODES;                       // N+1
    int*   eidx    = rowptr + N_NODES + 1;                // M
    int*   srcs    = eidx + M_EDGES;                      // M
    float* esum    = (float*)(srcs + M_EDGES);            // N*64 f32 (12.8 MB)
    short* attr_bf = (short*)(esum + (size_t)N_NODES * EDGE_F); // N_PAD*256 bf16

    hipMemsetAsync(fp_part, 0, 64 * OUT_DIM * sizeof(float), stream);
    hipMemsetAsync(deg, 0, N_NODES * sizeof(int), stream);

    k_init_attr<<<(N_PAD * 64 + 255) / 256, 256, 0, stream>>>(node_attr, attr, attr_bf);

    // CSR build (once, reused for all depths)
    k_degree<<<(M_EDGES + 255) / 256, 256, 0, stream>>>(edge_dst, deg);
    k_scan<<<1, 1024, 0, stream>>>(deg, rowptr);
    k_fill<<<(M_EDGES + 255) / 256, 256, 0, stream>>>(edge_dst, edge_src, deg, eidx, srcs);
    k_esum<<<(N_NODES * 16 + 255) / 256, 256, 0, stream>>>(edge_attr, rowptr, eidx, esum);

    // W_output -> bf16 fragment swizzle (all 4 depths)
    k_wswz<<<1024, 256, 0, stream>>>(W_output, Wz);

    k_fp_mfma<<<N_PAD / 32, 1024, 0, stream>>>(attr_bf, Wz, b_output, fp_part);

    for (int d = 1; d <= DEPTH; d++) {
        k_gather<<<(N_NODES * 64 + 255) / 256, 256, 0, stream>>>(
            attr, rowptr, srcs, esum, agg);
        k_inner<<<(N_NODES + 31) / 32, 256, 0, stream>>>(
            attr, agg, W_inner + (size_t)(d - 1) * DIM * DIM,
            b_inner + (size_t)(d - 1) * DIM, attr, attr_bf);
        k_fp_mfma<<<N_PAD / 32, 1024, 0, stream>>>(
            attr_bf, Wz + (size_t)d * 65536 * 8,
            b_output + (size_t)d * OUT_DIM, fp_part);
    }
    k_fp_reduce<<<OUT_DIM / 256, 256, 0, stream>>>(fp_part, fp);
}